// Round 16
// baseline (3310.418 us; speedup 1.0000x reference)
//
#include <hip/hip_runtime.h>
#include <cstdint>
#include <cstddef>

// GPT-12-layer forward, bf16 MFMA pipeline.
//   residual stream: bf16 (LN outputs), rows = b*512+l (M=8192), row-major
//   weights pre-transposed per layer to Wt[N][K] bf16
// qkv GEMM: gemm512 (128x256, 512 thr, 2-phase). fc GEMM: gemm_fc8 --
//   128x256, 512 thr, 96KB LDS double-buffer, 4 phases/K-tile, counted
//   vmcnt(6) (never 0 mid-loop), setprio MFMA clusters; grid 768 = exactly
//   3 rounds of 256 CUs (no tail tax). gelu epilogue.
// proj/mlp: 128x128 + split-K2, bf16 partials; LN does 3-input add.
// attn: flash-style QBLK=128, 8 waves; V staged subtiled, consumed via
//   ds_read_b64_tr_b16 (HW transpose). No V^T buffer.
// All GEMM LDS XOR-swizzled (16B slot ^= row&7) via pre-swizzled global source.

#define LSEQ 512
#define NBATCH 16
#define EDIM 768
#define NHEAD 12
#define NLAYER 12

typedef __attribute__((ext_vector_type(8))) short short8;
typedef __attribute__((ext_vector_type(4))) short short4v;
typedef __attribute__((ext_vector_type(4))) float f32x4;

__device__ __forceinline__ short f2bf(float f) {
  union { float f; unsigned u; } x; x.f = f;
  return (short)((x.u + 0x7FFFu + ((x.u >> 16) & 1u)) >> 16);  // RNE
}
__device__ __forceinline__ float bf2f(short s) {
  union { unsigned u; float f; } x; x.u = ((unsigned)(unsigned short)s) << 16;
  return x.f;
}

__device__ __forceinline__ void gload_lds16(const void* g, void* l) {
  __builtin_amdgcn_global_load_lds(
      (__attribute__((address_space(1))) void*)(void*)g,
      (__attribute__((address_space(3))) void*)l, 16, 0, 0);
}

// 32-bit LDS byte offset of a __shared__ address (AS3 pointer value)
__device__ __forceinline__ unsigned lds_addr(const void* p) {
  return (unsigned)(size_t)(__attribute__((address_space(3))) const void*)p;
}

// ---------------- weight transpose + bf16 convert: W[K][N] f32 -> Wt[N][K] bf16
__global__ __launch_bounds__(256) void wt_transpose(const float* __restrict__ W,
                                                    short* __restrict__ Wt,
                                                    int K, int N) {
  __shared__ float tile[32][33];
  const int n0 = blockIdx.x * 32, k0 = blockIdx.y * 32;
  const size_t lo = (size_t)blockIdx.z * K * N;
  const float* Ws = W + lo;
  short* Wd = Wt + lo;
  const int tx = threadIdx.x & 31, ty = threadIdx.x >> 5;  // 32 x 8
#pragma unroll
  for (int i = 0; i < 4; ++i)
    tile[ty + i * 8][tx] = Ws[(size_t)(k0 + ty + i * 8) * N + n0 + tx];
  __syncthreads();
#pragma unroll
  for (int i = 0; i < 4; ++i)
    Wd[(size_t)(n0 + ty + i * 8) * K + k0 + tx] = f2bf(tile[tx][ty + i * 8]);
}

// ---------------- embed: hbf[b*L+l][e] = bf16(x[l][b][e] + pos[l][e])
__global__ __launch_bounds__(256) void embed_k(const float* __restrict__ x,
                                               const float* __restrict__ pos,
                                               short* __restrict__ hbf) {
  const int row = blockIdx.x;  // b*512 + l
  const int b = row >> 9, lp = row & 511;
  const int t = threadIdx.x;
#pragma unroll
  for (int i = 0; i < 3; ++i) {
    const int e = t + i * 256;
    float v = x[(size_t)(lp * 16 + b) * 768 + e] + pos[(size_t)lp * 768 + e];
    hbf[(size_t)row * 768 + e] = f2bf(v);
  }
}

// ---------------- fused residual-add + LayerNorm, wave-per-row
template <int FINAL>
__global__ __launch_bounds__(256) void ln_fused(const short* __restrict__ A,
                                                const short* __restrict__ B0,
                                                const short* __restrict__ B1,
                                                const float* __restrict__ g,
                                                const float* __restrict__ be,
                                                void* __restrict__ out) {
  const int row = blockIdx.x * 4 + (threadIdx.x >> 6);
  const int l = threadIdx.x & 63;
  const size_t base = (size_t)row * 768;
  float v[12];
  float s1 = 0.f, s2 = 0.f;
#pragma unroll
  for (int j = 0; j < 3; ++j) {
    const int e = j * 256 + l * 4;
    short4v a = *(const short4v*)&A[base + e];
    short4v b0 = *(const short4v*)&B0[base + e];
    short4v b1 = *(const short4v*)&B1[base + e];
#pragma unroll
    for (int q = 0; q < 4; ++q) {
      float x = bf2f(a[q]) + bf2f(b0[q]) + bf2f(b1[q]);
      v[j * 4 + q] = x; s1 += x; s2 += x * x;
    }
  }
#pragma unroll
  for (int m = 1; m < 64; m <<= 1) {
    s1 += __shfl_xor(s1, m);
    s2 += __shfl_xor(s2, m);
  }
  const float mu = s1 * (1.f / 768.f);
  const float rs = rsqrtf(s2 * (1.f / 768.f) - mu * mu + 1e-5f);
  size_t obase = base;
  if constexpr (FINAL) {
    const int b = row >> 9, lp = row & 511;   // row = b*512+lp -> out lp*16+b
    obase = (size_t)(lp * 16 + b) * 768;
  }
#pragma unroll
  for (int j = 0; j < 3; ++j) {
    const int e = j * 256 + l * 4;
    f32x4 gv = *(const f32x4*)&g[e];
    f32x4 bv = *(const f32x4*)&be[e];
    if constexpr (FINAL) {
      f32x4 of;
#pragma unroll
      for (int q = 0; q < 4; ++q)
        of[q] = (v[j * 4 + q] - mu) * rs * gv[q] + bv[q];
      *(f32x4*)&((float*)out)[obase + e] = of;
    } else {
      short4v ob;
#pragma unroll
      for (int q = 0; q < 4; ++q)
        ob[q] = f2bf((v[j * 4 + q] - mu) * rs * gv[q] + bv[q]);
      *(short4v*)&((short*)out)[obase + e] = ob;
    }
  }
}

// ---------------- 512-thr 128x256 GEMM, 2-phase (qkv): bf16 out
__global__ __launch_bounds__(512) void gemm512(const short* __restrict__ A,
                                               const short* __restrict__ Bt,
                                               const float* __restrict__ bias,
                                               short* __restrict__ C,
                                               int N, int K) {
  constexpr int BK = 64;
  __shared__ alignas(16) short Alds[128 * BK];
  __shared__ alignas(16) short Blds[256 * BK];
  const int t = threadIdx.x;
  const int w = t >> 6, l = t & 63;
  const int wr = w >> 2, wc = w & 3;
  const int l15 = l & 15, lhi = l >> 4;
  const int rowA0 = blockIdx.x * 128;
  const int rowB0 = blockIdx.y * 256;

  f32x4 acc[4][4];
#pragma unroll
  for (int mi = 0; mi < 4; ++mi)
#pragma unroll
    for (int ni = 0; ni < 4; ++ni) acc[mi][ni] = (f32x4){0.f, 0.f, 0.f, 0.f};

  const int srl = w * 8 + (l >> 3);
  const int ss = l & 7;

  const short* aptr[2];
#pragma unroll
  for (int i = 0; i < 2; ++i) {
    const int r = i * 64 + srl;
    aptr[i] = A + (size_t)(rowA0 + r) * K + ((ss ^ (r & 7)) << 3);
  }
  const short* bptr[4];
#pragma unroll
  for (int i = 0; i < 4; ++i) {
    const int r = i * 64 + srl;
    bptr[i] = Bt + (size_t)(rowB0 + r) * K + ((ss ^ (r & 7)) << 3);
  }

  for (int kt = 0; kt < K; kt += BK) {
#pragma unroll
    for (int i = 0; i < 2; ++i) {
      gload_lds16(aptr[i], &Alds[(i * 64 + w * 8) * BK]);
      aptr[i] += BK;
    }
#pragma unroll
    for (int i = 0; i < 4; ++i) {
      gload_lds16(bptr[i], &Blds[(i * 64 + w * 8) * BK]);
      bptr[i] += BK;
    }
    __syncthreads();
    short8 af[4][2], bfr[4][2];
#pragma unroll
    for (int mi = 0; mi < 4; ++mi) {
      const int r = wr * 64 + mi * 16 + l15;
#pragma unroll
      for (int kc = 0; kc < 2; ++kc)
        af[mi][kc] = *(const short8*)
            &Alds[r * BK + ((((kc << 2) | lhi) ^ (r & 7)) << 3)];
    }
#pragma unroll
    for (int ni = 0; ni < 4; ++ni) {
      const int r = wc * 64 + ni * 16 + l15;
#pragma unroll
      for (int kc = 0; kc < 2; ++kc)
        bfr[ni][kc] = *(const short8*)
            &Blds[r * BK + ((((kc << 2) | lhi) ^ (r & 7)) << 3)];
    }
#pragma unroll
    for (int mi = 0; mi < 4; ++mi)
#pragma unroll
      for (int ni = 0; ni < 4; ++ni)
#pragma unroll
        for (int kc = 0; kc < 2; ++kc)
          acc[mi][ni] = __builtin_amdgcn_mfma_f32_16x16x32_bf16(
              af[mi][kc], bfr[ni][kc], acc[mi][ni], 0, 0, 0);
    __syncthreads();
  }

  float bv[4];
#pragma unroll
  for (int ni = 0; ni < 4; ++ni) bv[ni] = bias[rowB0 + wc * 64 + ni * 16 + l15];
#pragma unroll
  for (int mi = 0; mi < 4; ++mi) {
#pragma unroll
    for (int ni = 0; ni < 4; ++ni) {
      const int col = rowB0 + wc * 64 + ni * 16 + l15;
#pragma unroll
      for (int i = 0; i < 4; ++i) {
        const int row = rowA0 + wr * 64 + mi * 16 + lhi * 4 + i;
        C[(size_t)row * N + col] = f2bf(acc[mi][ni][i] + bv[ni]);
      }
    }
  }
}

// ---------------- fc GEMM: 128x256, 512 thr, DOUBLE-BUFFERED 4-phase/K-tile,
// counted vmcnt(6) (drain only on last tile), setprio MFMA. gelu(bf16) out.
// Grid 64x12 = 768 blocks = exactly 3 rounds at 1 block/CU (96 KB LDS).
__global__ __launch_bounds__(512, 1) void gemm_fc8(const short* __restrict__ A,
                                                   const short* __restrict__ Bt,
                                                   const float* __restrict__ bias,
                                                   short* __restrict__ C,
                                                   int N, int K) {
  constexpr int BK = 64;
  __shared__ alignas(16) short Ab[2][128 * BK];
  __shared__ alignas(16) short Bb[2][256 * BK];
  const int t = threadIdx.x;
  const int w = t >> 6, l = t & 63;
  const int wr = w >> 2, wc = w & 3;
  const int l15 = l & 15, lhi = l >> 4;
  const int rowA0 = blockIdx.x * 128;
  const int rowB0 = blockIdx.y * 256;

  f32x4 acc[4][4];
#pragma unroll
  for (int mi = 0; mi < 4; ++mi)
#pragma unroll
    for (int ni = 0; ni < 4; ++ni) acc[mi][ni] = (f32x4){0.f, 0.f, 0.f, 0.f};

  const int srl = w * 8 + (l >> 3);
  const int ss = l & 7;

  const short* aptr[2];
#pragma unroll
  for (int i = 0; i < 2; ++i) {
    const int r = i * 64 + srl;
    aptr[i] = A + (size_t)(rowA0 + r) * K + ((ss ^ (r & 7)) << 3);
  }
  const short* bptr[4];
#pragma unroll
  for (int i = 0; i < 4; ++i) {
    const int r = i * 64 + srl;
    bptr[i] = Bt + (size_t)(rowB0 + r) * K + ((ss ^ (r & 7)) << 3);
  }

  // stage next K-tile (pointer bumps encode the tile sequence) into buf
  auto stage = [&](int buf) {
#pragma unroll
    for (int i = 0; i < 2; ++i) {
      gload_lds16(aptr[i], &Ab[buf][(i * 64 + w * 8) * BK]);
      aptr[i] += BK;
    }
#pragma unroll
    for (int i = 0; i < 4; ++i) {
      gload_lds16(bptr[i], &Bb[buf][(i * 64 + w * 8) * BK]);
      bptr[i] += BK;
    }
  };

  const int nk = K >> 6;  // 12
  stage(0);
  stage(1);  // 12 loads/thread in flight

  for (int tt = 0; tt < nk; ++tt) {
    const int c = tt & 1;
    // buf[c^1] finished being read at iter tt-1's final barrier -> safe to
    // overwrite with tile tt+1 now.
    if (tt >= 1 && tt + 1 < nk) stage(c ^ 1);
    // certify tile tt landed; tile tt+1's 6 loads stay in flight (T4)
    if (tt + 1 < nk) asm volatile("s_waitcnt vmcnt(6)" ::: "memory");
    else             asm volatile("s_waitcnt vmcnt(0)" ::: "memory");
    asm volatile("s_barrier" ::: "memory");  // all waves' tile-tt loads landed

    // phase 0: B all + A(mi=0); phases 1-3: A(mi) only. 8 MFMA per phase.
    short8 bfr[4][2];
#pragma unroll
    for (int ni = 0; ni < 4; ++ni) {
      const int r = wc * 64 + ni * 16 + l15;
#pragma unroll
      for (int kc = 0; kc < 2; ++kc)
        bfr[ni][kc] = *(const short8*)
            &Bb[c][r * BK + ((((kc << 2) | lhi) ^ (r & 7)) << 3)];
    }
#pragma unroll
    for (int mi = 0; mi < 4; ++mi) {
      short8 am[2];
      const int r = wr * 64 + mi * 16 + l15;
#pragma unroll
      for (int kc = 0; kc < 2; ++kc)
        am[kc] = *(const short8*)
            &Ab[c][r * BK + ((((kc << 2) | lhi) ^ (r & 7)) << 3)];
      asm volatile("s_waitcnt lgkmcnt(0)" ::: "memory");
      __builtin_amdgcn_sched_barrier(0);  // rule #18: pin MFMA below the wait
      __builtin_amdgcn_s_setprio(1);
#pragma unroll
      for (int ni = 0; ni < 4; ++ni)
#pragma unroll
        for (int kc = 0; kc < 2; ++kc)
          acc[mi][ni] = __builtin_amdgcn_mfma_f32_16x16x32_bf16(
              am[kc], bfr[ni][kc], acc[mi][ni], 0, 0, 0);
      __builtin_amdgcn_s_setprio(0);
      asm volatile("s_barrier" ::: "memory");  // phase fence; mi=3's barrier
                                               // certifies buf[c] fully read
    }
  }

  float bv[4];
#pragma unroll
  for (int ni = 0; ni < 4; ++ni) bv[ni] = bias[rowB0 + wc * 64 + ni * 16 + l15];
#pragma unroll
  for (int mi = 0; mi < 4; ++mi) {
#pragma unroll
    for (int ni = 0; ni < 4; ++ni) {
      const int col = rowB0 + wc * 64 + ni * 16 + l15;
#pragma unroll
      for (int i = 0; i < 4; ++i) {
        const int row = rowA0 + wr * 64 + mi * 16 + lhi * 4 + i;
        float v = acc[mi][ni][i] + bv[ni];
        // gelu_new via sigmoid: 0.5x(1+tanh z) = x / (1 + exp(-2z))
        float pz = v * fmaf(0.044715f, v * v, 1.0f);
        float e = __expf(-1.5957691216057308f * pz);
        float r = __builtin_amdgcn_rcpf(1.0f + e);
        C[(size_t)row * N + col] = f2bf(v * r);
      }
    }
  }
}

// ---------------- split-K GEMM for N=768 (proj, mlp): 128x128 tile, BK=64,
// blockIdx.z = K-half. Partial z writes bf16 to C + z*M*N; bias only in z=0.
__global__ __launch_bounds__(256) void gemm_pk(const short* __restrict__ A,
                                               const short* __restrict__ Bt,
                                               const float* __restrict__ bias,
                                               short* __restrict__ C,
                                               int N, int Kfull) {
  constexpr int BK = 64;
  __shared__ alignas(16) short Alds[128 * BK];
  __shared__ alignas(16) short Blds[128 * BK];
  const int t = threadIdx.x;
  const int w = t >> 6, l = t & 63;
  const int wr = w >> 1, wc = w & 1;
  const int l15 = l & 15, lhi = l >> 4;
  const int rowA0 = blockIdx.x * 128;
  const int rowB0 = blockIdx.y * 128;
  const int z = blockIdx.z;
  const int Ks = Kfull >> 1;
  const int koff = z * Ks;
  short* Cp = C + (size_t)z * 8192 * N;

  f32x4 acc[4][4];
#pragma unroll
  for (int mi = 0; mi < 4; ++mi)
#pragma unroll
    for (int ni = 0; ni < 4; ++ni) acc[mi][ni] = (f32x4){0.f, 0.f, 0.f, 0.f};

  const int srl = l >> 3;
  const int ss = l & 7;

  const short* aptr[4];
  const short* bptr[4];
#pragma unroll
  for (int i = 0; i < 4; ++i) {
    const int r = i * 32 + w * 8 + srl;
    aptr[i] = A + (size_t)(rowA0 + r) * Kfull + koff + ((ss ^ (r & 7)) << 3);
    bptr[i] = Bt + (size_t)(rowB0 + r) * Kfull + koff + ((ss ^ (r & 7)) << 3);
  }

  for (int kt = 0; kt < Ks; kt += BK) {
#pragma unroll
    for (int i = 0; i < 4; ++i) {
      gload_lds16(aptr[i], &Alds[i * 2048 + w * 512]);
      gload_lds16(bptr[i], &Blds[i * 2048 + w * 512]);
      aptr[i] += BK; bptr[i] += BK;
    }
    __syncthreads();
    short8 af[4][2], bfr[4][2];
#pragma unroll
    for (int mi = 0; mi < 4; ++mi) {
      const int r = wr * 64 + mi * 16 + l15;
#pragma unroll
      for (int kc = 0; kc < 2; ++kc)
        af[mi][kc] = *(const short8*)
            &Alds[r * 64 + ((((kc << 2) | lhi) ^ (r & 7)) << 3)];
    }
#pragma unroll
    for (int ni = 0; ni < 4; ++ni) {
      const int r = wc * 64 + ni * 16 + l15;
#pragma unroll
      for (int kc = 0; kc < 2; ++kc)
        bfr[ni][kc] = *(const short8*)
            &Blds[r * 64 + ((((kc << 2) | lhi) ^ (r & 7)) << 3)];
    }
#pragma unroll
    for (int mi = 0; mi < 4; ++mi)
#pragma unroll
      for (int ni = 0; ni < 4; ++ni)
#pragma unroll
        for (int kc = 0; kc < 2; ++kc)
          acc[mi][ni] = __builtin_amdgcn_mfma_f32_16x16x32_bf16(
              af[mi][kc], bfr[ni][kc], acc[mi][ni], 0, 0, 0);
    __syncthreads();
  }

  float bv[4];
#pragma unroll
  for (int ni = 0; ni < 4; ++ni)
    bv[ni] = (z == 0) ? bias[rowB0 + wc * 64 + ni * 16 + l15] : 0.f;
#pragma unroll
  for (int mi = 0; mi < 4; ++mi) {
#pragma unroll
    for (int ni = 0; ni < 4; ++ni) {
      const int col = rowB0 + wc * 64 + ni * 16 + l15;
#pragma unroll
      for (int i = 0; i < 4; ++i) {
        const int row = rowA0 + wr * 64 + mi * 16 + lhi * 4 + i;
        Cp[(size_t)row * N + col] = f2bf(acc[mi][ni][i] + bv[ni]);
      }
    }
  }
}

// ---------------- flash attention: QBLK=128, block = (qb, head, batch),
// 8 waves. K staged XOR-swizzled from qkvb; V staged row-major SUBTILED
// [k/4][d/16][4][16] from qkvb, consumed via ds_read_b64_tr_b16.
__global__ __launch_bounds__(512) void attn_k(const short* __restrict__ qkv,
                                              const float* __restrict__ mask,
                                              short* __restrict__ o) {
  const int qb = blockIdx.x;   // 128-row q block (0..3)
  const int hh = blockIdx.y;
  const int b = blockIdx.z;
  const int t = threadIdx.x, w = t >> 6, l = t & 63;
  const int l15 = l & 15, lhi = l >> 4;
  __shared__ alignas(16) short Klds[64 * 64];
  __shared__ alignas(16) short Vlds[64 * 64];   // subtiled [k/4][d/16][4][16]
  __shared__ alignas(16) short Plds[8][16 * 72];

  short8 qa[2];
  {
    const size_t base =
        (size_t)(b * LSEQ + qb * 128 + w * 16 + l15) * 2304 + hh * 64;
    qa[0] = *(const short8*)&qkv[base + lhi * 8];
    qa[1] = *(const short8*)&qkv[base + 32 + lhi * 8];
  }
  float mrow[4] = {-1e30f, -1e30f, -1e30f, -1e30f};
  float lrow[4] = {0.f, 0.f, 0.f, 0.f};
  const f32x4 zero4 = {0.f, 0.f, 0.f, 0.f};
  f32x4 oacc[4];
#pragma unroll
  for (int nt = 0; nt < 4; ++nt) oacc[nt] = zero4;

  const int kr = t >> 3, sl = t & 7;
  const int vk = 4 * (t >> 5) + ((t & 7) >> 1);
  const int vd = 16 * ((t >> 3) & 3) + 8 * (t & 1);
  const unsigned vb32 = lds_addr(Vlds) + (unsigned)(lhi * 1024 + l15 * 8);

  const int nkt = qb * 2 + 2;  // causal: tiles up to the 128-row diagonal
  for (int kt = 0; kt < nkt; ++kt) {
    __syncthreads();  // previous iteration's K/V reads complete
    gload_lds16(qkv + (size_t)(b * LSEQ + kt * 64 + kr) * 2304 + 768 +
                    hh * 64 + ((sl ^ (kr & 7)) << 3),
                &Klds[(w * 8) * 64]);
    gload_lds16(qkv + (size_t)(b * LSEQ + kt * 64 + vk) * 2304 + 1536 +
                    hh * 64 + vd,
                &Vlds[(w * 8) * 64]);
    __syncthreads();  // implicit vmcnt(0): tiles resident

    f32x4 s[4];
#pragma unroll
    for (int jt = 0; jt < 4; ++jt) {
      f32x4 z = zero4;
#pragma unroll
      for (int kc = 0; kc < 2; ++kc) {
        const int rowk = jt * 16 + l15;
        short8 kb = *(const short8*)((char*)Klds +
                     ((rowk * 128 + kc * 64 + lhi * 16) ^ ((rowk & 7) << 4)));
        z = __builtin_amdgcn_mfma_f32_16x16x32_bf16(qa[kc], kb, z, 0, 0, 0);
      }
      s[jt] = z;
    }

    float addm[4];
#pragma unroll
    for (int jt = 0; jt < 4; ++jt)
      addm[jt] = (1.0f - mask[b * LSEQ + kt * 64 + jt * 16 + l15]) *
                 -3.402823466e38f;
#pragma unroll
    for (int jt = 0; jt < 4; ++jt) {
      const int colg = kt * 64 + jt * 16 + l15;
#pragma unroll
      for (int i = 0; i < 4; ++i) {
        const int rowg = qb * 128 + w * 16 + lhi * 4 + i;
        float sv = s[jt][i] * 0.125f;
        if (colg > rowg) sv = -10000.0f;
        s[jt][i] = sv + addm[jt];
      }
    }

    float mnew[4], sc[4];
#pragma unroll
    for (int i = 0; i < 4; ++i) {
      float tm = fmaxf(fmaxf(s[0][i], s[1][i]), fmaxf(s[2][i], s[3][i]));
#pragma unroll
      for (int mm = 1; mm < 16; mm <<= 1) tm = fmaxf(tm, __shfl_xor(tm, mm));
      mnew[i] = fmaxf(mrow[i], tm);
      sc[i] = __expf(mrow[i] - mnew[i]);
      mrow[i] = mnew[i];
    }
#pragma unroll
    for (int i = 0; i < 4; ++i) {
      float ts = 0.f;
#pragma unroll
      for (int jt = 0; jt < 4; ++jt) {
        float p = __expf(s[jt][i] - mnew[i]);
        s[jt][i] = p;
        ts += p;
      }
#pragma unroll
      for (int mm = 1; mm < 16; mm <<= 1) ts += __shfl_xor(ts, mm);
      lrow[i] = lrow[i] * sc[i] + ts;
      oacc[0][i] *= sc[i]; oacc[1][i] *= sc[i];
      oacc[2][i] *= sc[i]; oacc[3][i] *= sc[i];
    }

    short* Pw = &Plds[w][0];
#pragma unroll
    for (int jt = 0; jt < 4; ++jt)
#pragma unroll
      for (int i = 0; i < 4; ++i)
        Pw[(lhi * 4 + i) * 72 + jt * 16 + l15] = f2bf(s[jt][i]);
    short8 pa[2];
#pragma unroll
    for (int kc = 0; kc < 2; ++kc)
      pa[kc] = *(const short8*)&Pw[l15 * 72 + kc * 32 + lhi * 8];

#pragma unroll
    for (int nt = 0; nt < 4; ++nt) {
      unsigned long r00, r01, r10, r11;
      asm volatile("ds_read_b64_tr_b16 %0, %1 offset:0"
                   : "=v"(r00) : "v"(vb32 + (unsigned)(nt * 128)));
      asm volatile("ds_read_b64_tr_b16 %0, %1 offset:512"
                   : "=v"(r01) : "v"(vb32 + (unsigned)(nt * 128)));
      asm volatile("ds_read_b64_tr_b16 %0, %1 offset:4096"
                   : "=v"(r10) : "v"(vb32 + (unsigned)(nt * 128)));
      asm volatile("ds_read_b64_tr_b16 %0, %1 offset:4608"
                   : "=v"(r11) : "v"(vb32 + (unsigned)(nt * 128)));
      asm volatile("s_waitcnt lgkmcnt(0)" ::: "memory");
      __builtin_amdgcn_sched_barrier(0);
      union { struct { unsigned long a, b; } u; short8 s; } v0, v1;
      v0.u.a = r00; v0.u.b = r01;
      v1.u.a = r10; v1.u.b = r11;
      oacc[nt] = __builtin_amdgcn_mfma_f32_16x16x32_bf16(pa[0], v0.s,
                                                         oacc[nt], 0, 0, 0);
      oacc[nt] = __builtin_amdgcn_mfma_f32_16x16x32_bf16(pa[1], v1.s,
                                                         oacc[nt], 0, 0, 0);
    }
  }

#pragma unroll
  for (int i = 0; i < 4; ++i) {
    const size_t row = (size_t)(b * LSEQ + qb * 128 + w * 16 + lhi * 4 + i);
    const float inv = 1.0f / lrow[i];
#pragma unroll
    for (int nt = 0; nt < 4; ++nt)
      o[row * 768 + hh * 64 + nt * 16 + l15] = f2bf(oacc[nt][i] * inv);
  }
}

// =====================================================================
extern "C" void kernel_launch(void* const* d_in, const int* in_sizes, int n_in,
                              void* d_out, int out_size, void* d_ws,
                              size_t ws_size, hipStream_t stream) {
  const float* x    = (const float*)d_in[0];
  const float* mask = (const float*)d_in[1];
  const float* pos  = (const float*)d_in[2];
  const float* caw  = (const float*)d_in[3];
  const float* cab  = (const float*)d_in[4];
  const float* apw  = (const float*)d_in[5];
  const float* apb  = (const float*)d_in[6];
  const float* g1   = (const float*)d_in[7];
  const float* b1   = (const float*)d_in[8];
  const float* fw   = (const float*)d_in[9];
  const float* fb   = (const float*)d_in[10];
  const float* pw   = (const float*)d_in[11];
  const float* pb   = (const float*)d_in[12];
  const float* g2   = (const float*)d_in[13];
  const float* b2   = (const float*)d_in[14];

  char* ws = (char*)d_ws;
  size_t off = 0;
  auto alloc = [&](size_t bytes) {
    size_t o = off;
    off += (bytes + 255) & ~(size_t)255;
    return o;
  };
  short* hbf  = (short*)(ws + alloc(8192ull * 768 * 2));   // residual (bf16)
  short* nbf  = (short*)(ws + alloc(8192ull * 768 * 2));   // LN1 out (bf16)
  short* qkvb = (short*)(ws + alloc(8192ull * 2304 * 2));  // Q,K,V row-major
  short* obf  = (short*)(ws + alloc(8192ull * 768 * 2));
  short* aout = (short*)(ws + alloc(2ull * 8192 * 768 * 2));  // split-K partials
  short* gbf  = (short*)(ws + alloc(8192ull * 3072 * 2));
  short* wt_attn = (short*)(ws + alloc(12ull * 768 * 2304 * 2));
  short* wt_proj = (short*)(ws + alloc(12ull * 768 * 768 * 2));
  short* wt_fc   = (short*)(ws + alloc(12ull * 768 * 3072 * 2));
  short* wt_mlp  = (short*)(ws + alloc(12ull * 3072 * 768 * 2));
  short* aout1 = aout + 8192ull * 768;
  (void)ws_size; (void)in_sizes; (void)n_in; (void)out_size;

  wt_transpose<<<dim3(2304 / 32, 768 / 32, 12), 256, 0, stream>>>(caw, wt_attn, 768, 2304);
  wt_transpose<<<dim3(768 / 32, 768 / 32, 12), 256, 0, stream>>>(apw, wt_proj, 768, 768);
  wt_transpose<<<dim3(3072 / 32, 768 / 32, 12), 256, 0, stream>>>(fw, wt_fc, 768, 3072);
  wt_transpose<<<dim3(768 / 32, 3072 / 32, 12), 256, 0, stream>>>(pw, wt_mlp, 3072, 768);

  embed_k<<<8192, 256, 0, stream>>>(x, pos, hbf);

  for (int L = 0; L < 12; ++L) {
    gemm512<<<dim3(64, 9), 512, 0, stream>>>(
        hbf, wt_attn + (size_t)L * 2304 * 768, cab + (size_t)L * 2304, qkvb, 2304, 768);
    attn_k<<<dim3(4, 12, 16), 512, 0, stream>>>(qkvb, mask, obf);
    gemm_pk<<<dim3(64, 6, 2), 256, 0, stream>>>(
        obf, wt_proj + (size_t)L * 768 * 768, apb + (size_t)L * 768, aout, 768, 768);
    ln_fused<0><<<2048, 256, 0, stream>>>(hbf, aout, aout1, g1 + (size_t)L * 768,
                                          b1 + (size_t)L * 768, nbf);
    gemm_fc8<<<dim3(64, 12), 512, 0, stream>>>(
        nbf, wt_fc + (size_t)L * 768 * 3072, fb + (size_t)L * 3072, gbf, 3072, 768);
    gemm_pk<<<dim3(64, 6, 2), 256, 0, stream>>>(
        gbf, wt_mlp + (size_t)L * 3072 * 768, pb + (size_t)L * 768, aout, 768, 3072);
    if (L < 11) {
      ln_fused<0><<<2048, 256, 0, stream>>>(nbf, aout, aout1, g2 + (size_t)L * 768,
                                            b2 + (size_t)L * 768, hbf);
    } else {
      ln_fused<1><<<2048, 256, 0, stream>>>(nbf, aout, aout1, g2 + (size_t)L * 768,
                                            b2 + (size_t)L * 768, (float*)d_out);
    }
  }
}

// Round 17
// 3037.238 us; speedup vs baseline: 1.0899x; 1.0899x over previous
//
#include <hip/hip_runtime.h>
#include <cstdint>
#include <cstddef>

// GPT-12-layer forward, bf16 MFMA pipeline.  (R15 configuration — session best)
//   residual stream: bf16 (LN outputs), rows = b*512+l (M=8192), row-major
//   weights pre-transposed per layer to Wt[N][K] bf16
// qkv + fc GEMMs: gemm512 template, 128x256 tile, 512 thr, 8 waves 2Mx4N,
//   BK=64, 2-phase; EPI=1 bf16 (qkv), EPI=2 gelu (fc). All writes coalesced.
// proj/mlp: 128x128 + split-K2, bf16 partials; LN does 3-input add.
// attn: flash-style QBLK=128, 8 waves. K staged XOR-swizzled; V staged
//   ROW-MAJOR SUBTILED [k/4][d/16][4][16] straight from qkvb and consumed
//   via ds_read_b64_tr_b16 (per-lane addr = subtile_base + (l&15)*8 bytes).
// All GEMM LDS XOR-swizzled (16B slot ^= row&7) via pre-swizzled global source.

#define LSEQ 512
#define NBATCH 16
#define EDIM 768
#define NHEAD 12
#define NLAYER 12

typedef __attribute__((ext_vector_type(8))) short short8;
typedef __attribute__((ext_vector_type(4))) short short4v;
typedef __attribute__((ext_vector_type(4))) float f32x4;

__device__ __forceinline__ short f2bf(float f) {
  union { float f; unsigned u; } x; x.f = f;
  return (short)((x.u + 0x7FFFu + ((x.u >> 16) & 1u)) >> 16);  // RNE
}
__device__ __forceinline__ float bf2f(short s) {
  union { unsigned u; float f; } x; x.u = ((unsigned)(unsigned short)s) << 16;
  return x.f;
}

__device__ __forceinline__ void gload_lds16(const void* g, void* l) {
  __builtin_amdgcn_global_load_lds(
      (__attribute__((address_space(1))) void*)(void*)g,
      (__attribute__((address_space(3))) void*)l, 16, 0, 0);
}

// 32-bit LDS byte offset of a __shared__ address (AS3 pointer value)
__device__ __forceinline__ unsigned lds_addr(const void* p) {
  return (unsigned)(size_t)(__attribute__((address_space(3))) const void*)p;
}

// ---------------- weight transpose + bf16 convert: W[K][N] f32 -> Wt[N][K] bf16
__global__ __launch_bounds__(256) void wt_transpose(const float* __restrict__ W,
                                                    short* __restrict__ Wt,
                                                    int K, int N) {
  __shared__ float tile[32][33];
  const int n0 = blockIdx.x * 32, k0 = blockIdx.y * 32;
  const size_t lo = (size_t)blockIdx.z * K * N;
  const float* Ws = W + lo;
  short* Wd = Wt + lo;
  const int tx = threadIdx.x & 31, ty = threadIdx.x >> 5;  // 32 x 8
#pragma unroll
  for (int i = 0; i < 4; ++i)
    tile[ty + i * 8][tx] = Ws[(size_t)(k0 + ty + i * 8) * N + n0 + tx];
  __syncthreads();
#pragma unroll
  for (int i = 0; i < 4; ++i)
    Wd[(size_t)(n0 + ty + i * 8) * K + k0 + tx] = f2bf(tile[tx][ty + i * 8]);
}

// ---------------- embed: hbf[b*L+l][e] = bf16(x[l][b][e] + pos[l][e])
__global__ __launch_bounds__(256) void embed_k(const float* __restrict__ x,
                                               const float* __restrict__ pos,
                                               short* __restrict__ hbf) {
  const int row = blockIdx.x;  // b*512 + l
  const int b = row >> 9, lp = row & 511;
  const int t = threadIdx.x;
#pragma unroll
  for (int i = 0; i < 3; ++i) {
    const int e = t + i * 256;
    float v = x[(size_t)(lp * 16 + b) * 768 + e] + pos[(size_t)lp * 768 + e];
    hbf[(size_t)row * 768 + e] = f2bf(v);
  }
}

// ---------------- fused residual-add + LayerNorm, wave-per-row
// x = A(bf16 residual) + B0 + B1 (bf16 split-K partials); f32 math.
// FINAL=0: writes bf16 (next GEMM input AND next residual).
// FINAL=1: writes f32 to out[(l*16+b)*768+e] (harness output layout).
template <int FINAL>
__global__ __launch_bounds__(256) void ln_fused(const short* __restrict__ A,
                                                const short* __restrict__ B0,
                                                const short* __restrict__ B1,
                                                const float* __restrict__ g,
                                                const float* __restrict__ be,
                                                void* __restrict__ out) {
  const int row = blockIdx.x * 4 + (threadIdx.x >> 6);
  const int l = threadIdx.x & 63;
  const size_t base = (size_t)row * 768;
  float v[12];
  float s1 = 0.f, s2 = 0.f;
#pragma unroll
  for (int j = 0; j < 3; ++j) {
    const int e = j * 256 + l * 4;
    short4v a = *(const short4v*)&A[base + e];
    short4v b0 = *(const short4v*)&B0[base + e];
    short4v b1 = *(const short4v*)&B1[base + e];
#pragma unroll
    for (int q = 0; q < 4; ++q) {
      float x = bf2f(a[q]) + bf2f(b0[q]) + bf2f(b1[q]);
      v[j * 4 + q] = x; s1 += x; s2 += x * x;
    }
  }
#pragma unroll
  for (int m = 1; m < 64; m <<= 1) {
    s1 += __shfl_xor(s1, m);
    s2 += __shfl_xor(s2, m);
  }
  const float mu = s1 * (1.f / 768.f);
  const float rs = rsqrtf(s2 * (1.f / 768.f) - mu * mu + 1e-5f);
  size_t obase = base;
  if constexpr (FINAL) {
    const int b = row >> 9, lp = row & 511;   // row = b*512+lp -> out lp*16+b
    obase = (size_t)(lp * 16 + b) * 768;
  }
#pragma unroll
  for (int j = 0; j < 3; ++j) {
    const int e = j * 256 + l * 4;
    f32x4 gv = *(const f32x4*)&g[e];
    f32x4 bv = *(const f32x4*)&be[e];
    if constexpr (FINAL) {
      f32x4 of;
#pragma unroll
      for (int q = 0; q < 4; ++q)
        of[q] = (v[j * 4 + q] - mu) * rs * gv[q] + bv[q];
      *(f32x4*)&((float*)out)[obase + e] = of;
    } else {
      short4v ob;
#pragma unroll
      for (int q = 0; q < 4; ++q)
        ob[q] = f2bf((v[j * 4 + q] - mu) * rs * gv[q] + bv[q]);
      *(short4v*)&((short*)out)[obase + e] = ob;
    }
  }
}

// ---------------- 512-thr 128x256 GEMM (qkv, fc): C = A * Bt^T + bias
// 8 waves 2Mx4N (64x64/wave), BK=64, 48 KB LDS, 2-phase.
// EPI: 1 = bf16 out, 2 = gelu(bf16) out
template <int EPI>
__global__ __launch_bounds__(512) void gemm512(const short* __restrict__ A,
                                               const short* __restrict__ Bt,
                                               const float* __restrict__ bias,
                                               short* __restrict__ C,
                                               int N, int K) {
  constexpr int BK = 64;
  __shared__ alignas(16) short Alds[128 * BK];
  __shared__ alignas(16) short Blds[256 * BK];
  const int t = threadIdx.x;
  const int w = t >> 6, l = t & 63;
  const int wr = w >> 2, wc = w & 3;
  const int l15 = l & 15, lhi = l >> 4;
  const int rowA0 = blockIdx.x * 128;
  const int rowB0 = blockIdx.y * 256;

  f32x4 acc[4][4];
#pragma unroll
  for (int mi = 0; mi < 4; ++mi)
#pragma unroll
    for (int ni = 0; ni < 4; ++ni) acc[mi][ni] = (f32x4){0.f, 0.f, 0.f, 0.f};

  const int srl = w * 8 + (l >> 3);
  const int ss = l & 7;

  const short* aptr[2];
#pragma unroll
  for (int i = 0; i < 2; ++i) {
    const int r = i * 64 + srl;
    aptr[i] = A + (size_t)(rowA0 + r) * K + ((ss ^ (r & 7)) << 3);
  }
  const short* bptr[4];
#pragma unroll
  for (int i = 0; i < 4; ++i) {
    const int r = i * 64 + srl;
    bptr[i] = Bt + (size_t)(rowB0 + r) * K + ((ss ^ (r & 7)) << 3);
  }

  for (int kt = 0; kt < K; kt += BK) {
#pragma unroll
    for (int i = 0; i < 2; ++i) {
      gload_lds16(aptr[i], &Alds[(i * 64 + w * 8) * BK]);
      aptr[i] += BK;
    }
#pragma unroll
    for (int i = 0; i < 4; ++i) {
      gload_lds16(bptr[i], &Blds[(i * 64 + w * 8) * BK]);
      bptr[i] += BK;
    }
    __syncthreads();
    short8 af[4][2], bfr[4][2];
#pragma unroll
    for (int mi = 0; mi < 4; ++mi) {
      const int r = wr * 64 + mi * 16 + l15;
#pragma unroll
      for (int kc = 0; kc < 2; ++kc)
        af[mi][kc] = *(const short8*)
            &Alds[r * BK + ((((kc << 2) | lhi) ^ (r & 7)) << 3)];
    }
#pragma unroll
    for (int ni = 0; ni < 4; ++ni) {
      const int r = wc * 64 + ni * 16 + l15;
#pragma unroll
      for (int kc = 0; kc < 2; ++kc)
        bfr[ni][kc] = *(const short8*)
            &Blds[r * BK + ((((kc << 2) | lhi) ^ (r & 7)) << 3)];
    }
#pragma unroll
    for (int mi = 0; mi < 4; ++mi)
#pragma unroll
      for (int ni = 0; ni < 4; ++ni)
#pragma unroll
        for (int kc = 0; kc < 2; ++kc)
          acc[mi][ni] = __builtin_amdgcn_mfma_f32_16x16x32_bf16(
              af[mi][kc], bfr[ni][kc], acc[mi][ni], 0, 0, 0);
    __syncthreads();
  }

  float bv[4];
#pragma unroll
  for (int ni = 0; ni < 4; ++ni) bv[ni] = bias[rowB0 + wc * 64 + ni * 16 + l15];
#pragma unroll
  for (int mi = 0; mi < 4; ++mi) {
#pragma unroll
    for (int ni = 0; ni < 4; ++ni) {
      const int col = rowB0 + wc * 64 + ni * 16 + l15;
#pragma unroll
      for (int i = 0; i < 4; ++i) {
        const int row = rowA0 + wr * 64 + mi * 16 + lhi * 4 + i;
        float v = acc[mi][ni][i] + bv[ni];
        if constexpr (EPI == 1) {
          C[(size_t)row * N + col] = f2bf(v);
        } else {
          // gelu_new via sigmoid: 0.5x(1+tanh z) = x / (1 + exp(-2z))
          float pz = v * fmaf(0.044715f, v * v, 1.0f);
          float e = __expf(-1.5957691216057308f * pz);
          float r = __builtin_amdgcn_rcpf(1.0f + e);
          C[(size_t)row * N + col] = f2bf(v * r);
        }
      }
    }
  }
}

// ---------------- split-K GEMM for N=768 (proj, mlp): 128x128 tile, BK=64,
// blockIdx.z = K-half. Partial z writes bf16 to C + z*M*N; bias only in z=0.
__global__ __launch_bounds__(256) void gemm_pk(const short* __restrict__ A,
                                               const short* __restrict__ Bt,
                                               const float* __restrict__ bias,
                                               short* __restrict__ C,
                                               int N, int Kfull) {
  constexpr int BK = 64;
  __shared__ alignas(16) short Alds[128 * BK];
  __shared__ alignas(16) short Blds[128 * BK];
  const int t = threadIdx.x;
  const int w = t >> 6, l = t & 63;
  const int wr = w >> 1, wc = w & 1;
  const int l15 = l & 15, lhi = l >> 4;
  const int rowA0 = blockIdx.x * 128;
  const int rowB0 = blockIdx.y * 128;
  const int z = blockIdx.z;
  const int Ks = Kfull >> 1;
  const int koff = z * Ks;
  short* Cp = C + (size_t)z * 8192 * N;

  f32x4 acc[4][4];
#pragma unroll
  for (int mi = 0; mi < 4; ++mi)
#pragma unroll
    for (int ni = 0; ni < 4; ++ni) acc[mi][ni] = (f32x4){0.f, 0.f, 0.f, 0.f};

  const int srl = l >> 3;
  const int ss = l & 7;

  const short* aptr[4];
  const short* bptr[4];
#pragma unroll
  for (int i = 0; i < 4; ++i) {
    const int r = i * 32 + w * 8 + srl;
    aptr[i] = A + (size_t)(rowA0 + r) * Kfull + koff + ((ss ^ (r & 7)) << 3);
    bptr[i] = Bt + (size_t)(rowB0 + r) * Kfull + koff + ((ss ^ (r & 7)) << 3);
  }

  for (int kt = 0; kt < Ks; kt += BK) {
#pragma unroll
    for (int i = 0; i < 4; ++i) {
      gload_lds16(aptr[i], &Alds[i * 2048 + w * 512]);
      gload_lds16(bptr[i], &Blds[i * 2048 + w * 512]);
      aptr[i] += BK; bptr[i] += BK;
    }
    __syncthreads();
    short8 af[4][2], bfr[4][2];
#pragma unroll
    for (int mi = 0; mi < 4; ++mi) {
      const int r = wr * 64 + mi * 16 + l15;
#pragma unroll
      for (int kc = 0; kc < 2; ++kc)
        af[mi][kc] = *(const short8*)
            &Alds[r * 64 + ((((kc << 2) | lhi) ^ (r & 7)) << 3)];
    }
#pragma unroll
    for (int ni = 0; ni < 4; ++ni) {
      const int r = wc * 64 + ni * 16 + l15;
#pragma unroll
      for (int kc = 0; kc < 2; ++kc)
        bfr[ni][kc] = *(const short8*)
            &Blds[r * 64 + ((((kc << 2) | lhi) ^ (r & 7)) << 3)];
    }
#pragma unroll
    for (int mi = 0; mi < 4; ++mi)
#pragma unroll
      for (int ni = 0; ni < 4; ++ni)
#pragma unroll
        for (int kc = 0; kc < 2; ++kc)
          acc[mi][ni] = __builtin_amdgcn_mfma_f32_16x16x32_bf16(
              af[mi][kc], bfr[ni][kc], acc[mi][ni], 0, 0, 0);
    __syncthreads();
  }

  float bv[4];
#pragma unroll
  for (int ni = 0; ni < 4; ++ni)
    bv[ni] = (z == 0) ? bias[rowB0 + wc * 64 + ni * 16 + l15] : 0.f;
#pragma unroll
  for (int mi = 0; mi < 4; ++mi) {
#pragma unroll
    for (int ni = 0; ni < 4; ++ni) {
      const int col = rowB0 + wc * 64 + ni * 16 + l15;
#pragma unroll
      for (int i = 0; i < 4; ++i) {
        const int row = rowA0 + wr * 64 + mi * 16 + lhi * 4 + i;
        Cp[(size_t)row * N + col] = f2bf(acc[mi][ni][i] + bv[ni]);
      }
    }
  }
}

// ---------------- flash attention: QBLK=128, block = (qb, head, batch),
// 8 waves. K staged XOR-swizzled from qkvb; V staged row-major SUBTILED
// [k/4][d/16][4][16] from qkvb, consumed via ds_read_b64_tr_b16.
__global__ __launch_bounds__(512) void attn_k(const short* __restrict__ qkv,
                                              const float* __restrict__ mask,
                                              short* __restrict__ o) {
  const int qb = blockIdx.x;   // 128-row q block (0..3)
  const int hh = blockIdx.y;
  const int b = blockIdx.z;
  const int t = threadIdx.x, w = t >> 6, l = t & 63;
  const int l15 = l & 15, lhi = l >> 4;
  __shared__ alignas(16) short Klds[64 * 64];
  __shared__ alignas(16) short Vlds[64 * 64];   // subtiled [k/4][d/16][4][16]
  __shared__ alignas(16) short Plds[8][16 * 72];

  short8 qa[2];
  {
    const size_t base =
        (size_t)(b * LSEQ + qb * 128 + w * 16 + l15) * 2304 + hh * 64;
    qa[0] = *(const short8*)&qkv[base + lhi * 8];
    qa[1] = *(const short8*)&qkv[base + 32 + lhi * 8];
  }
  float mrow[4] = {-1e30f, -1e30f, -1e30f, -1e30f};
  float lrow[4] = {0.f, 0.f, 0.f, 0.f};
  const f32x4 zero4 = {0.f, 0.f, 0.f, 0.f};
  f32x4 oacc[4];
#pragma unroll
  for (int nt = 0; nt < 4; ++nt) oacc[nt] = zero4;

  const int kr = t >> 3, sl = t & 7;
  const int vk = 4 * (t >> 5) + ((t & 7) >> 1);
  const int vd = 16 * ((t >> 3) & 3) + 8 * (t & 1);
  const unsigned vb32 = lds_addr(Vlds) + (unsigned)(lhi * 1024 + l15 * 8);

  const int nkt = qb * 2 + 2;  // causal: tiles up to the 128-row diagonal
  for (int kt = 0; kt < nkt; ++kt) {
    __syncthreads();  // previous iteration's K/V reads complete
    gload_lds16(qkv + (size_t)(b * LSEQ + kt * 64 + kr) * 2304 + 768 +
                    hh * 64 + ((sl ^ (kr & 7)) << 3),
                &Klds[(w * 8) * 64]);
    gload_lds16(qkv + (size_t)(b * LSEQ + kt * 64 + vk) * 2304 + 1536 +
                    hh * 64 + vd,
                &Vlds[(w * 8) * 64]);
    __syncthreads();  // implicit vmcnt(0): tiles resident

    f32x4 s[4];
#pragma unroll
    for (int jt = 0; jt < 4; ++jt) {
      f32x4 z = zero4;
#pragma unroll
      for (int kc = 0; kc < 2; ++kc) {
        const int rowk = jt * 16 + l15;
        short8 kb = *(const short8*)((char*)Klds +
                     ((rowk * 128 + kc * 64 + lhi * 16) ^ ((rowk & 7) << 4)));
        z = __builtin_amdgcn_mfma_f32_16x16x32_bf16(qa[kc], kb, z, 0, 0, 0);
      }
      s[jt] = z;
    }

    float addm[4];
#pragma unroll
    for (int jt = 0; jt < 4; ++jt)
      addm[jt] = (1.0f - mask[b * LSEQ + kt * 64 + jt * 16 + l15]) *
                 -3.402823466e38f;
#pragma unroll
    for (int jt = 0; jt < 4; ++jt) {
      const int colg = kt * 64 + jt * 16 + l15;
#pragma unroll
      for (int i = 0; i < 4; ++i) {
        const int rowg = qb * 128 + w * 16 + lhi * 4 + i;
        float sv = s[jt][i] * 0.125f;
        if (colg > rowg) sv = -10000.0f;
        s[jt][i] = sv + addm[jt];
      }
    }

    float mnew[4], sc[4];
#pragma unroll
    for (int i = 0; i < 4; ++i) {
      float tm = fmaxf(fmaxf(s[0][i], s[1][i]), fmaxf(s[2][i], s[3][i]));
#pragma unroll
      for (int mm = 1; mm < 16; mm <<= 1) tm = fmaxf(tm, __shfl_xor(tm, mm));
      mnew[i] = fmaxf(mrow[i], tm);
      sc[i] = __expf(mrow[i] - mnew[i]);
      mrow[i] = mnew[i];
    }
#pragma unroll
    for (int i = 0; i < 4; ++i) {
      float ts = 0.f;
#pragma unroll
      for (int jt = 0; jt < 4; ++jt) {
        float p = __expf(s[jt][i] - mnew[i]);
        s[jt][i] = p;
        ts += p;
      }
#pragma unroll
      for (int mm = 1; mm < 16; mm <<= 1) ts += __shfl_xor(ts, mm);
      lrow[i] = lrow[i] * sc[i] + ts;
      oacc[0][i] *= sc[i]; oacc[1][i] *= sc[i];
      oacc[2][i] *= sc[i]; oacc[3][i] *= sc[i];
    }

    // P relayout via per-wave LDS buffer (wave-lockstep DS ordering; Plds[w]
    // is wave-private so no block barrier needed).
    short* Pw = &Plds[w][0];
#pragma unroll
    for (int jt = 0; jt < 4; ++jt)
#pragma unroll
      for (int i = 0; i < 4; ++i)
        Pw[(lhi * 4 + i) * 72 + jt * 16 + l15] = f2bf(s[jt][i]);
    short8 pa[2];
#pragma unroll
    for (int kc = 0; kc < 2; ++kc)
      pa[kc] = *(const short8*)&Pw[l15 * 72 + kc * 32 + lhi * 8];

    // O += P V : B-fragments via hardware transpose reads.
#pragma unroll
    for (int nt = 0; nt < 4; ++nt) {
      unsigned long r00, r01, r10, r11;
      asm volatile("ds_read_b64_tr_b16 %0, %1 offset:0"
                   : "=v"(r00) : "v"(vb32 + (unsigned)(nt * 128)));
      asm volatile("ds_read_b64_tr_b16 %0, %1 offset:512"
                   : "=v"(r01) : "v"(vb32 + (unsigned)(nt * 128)));
      asm volatile("ds_read_b64_tr_b16 %0, %1 offset:4096"
                   : "=v"(r10) : "v"(vb32 + (unsigned)(nt * 128)));
      asm volatile("ds_read_b64_tr_b16 %0, %1 offset:4608"
                   : "=v"(r11) : "v"(vb32 + (unsigned)(nt * 128)));
      asm volatile("s_waitcnt lgkmcnt(0)" ::: "memory");
      __builtin_amdgcn_sched_barrier(0);
      union { struct { unsigned long a, b; } u; short8 s; } v0, v1;
      v0.u.a = r00; v0.u.b = r01;
      v1.u.a = r10; v1.u.b = r11;
      oacc[nt] = __builtin_amdgcn_mfma_f32_16x16x32_bf16(pa[0], v0.s,
                                                         oacc[nt], 0, 0, 0);
      oacc[nt] = __builtin_amdgcn_mfma_f32_16x16x32_bf16(pa[1], v1.s,
                                                         oacc[nt], 0, 0, 0);
    }
  }

#pragma unroll
  for (int i = 0; i < 4; ++i) {
    const size_t row = (size_t)(b * LSEQ + qb * 128 + w * 16 + lhi * 4 + i);
    const float inv = 1.0f / lrow[i];
#pragma unroll
    for (int nt = 0; nt < 4; ++nt)
      o[row * 768 + hh * 64 + nt * 16 + l15] = f2bf(oacc[nt][i] * inv);
  }
}

// =====================================================================
extern "C" void kernel_launch(void* const* d_in, const int* in_sizes, int n_in,
                              void* d_out, int out_size, void* d_ws,
                              size_t ws_size, hipStream_t stream) {
  const float* x    = (const float*)d_in[0];
  const float* mask = (const float*)d_in[1];
  const float* pos  = (const float*)d_in[2];
  const float* caw  = (const float*)d_in[3];
  const float* cab  = (const float*)d_in[4];
  const float* apw  = (const float*)d_in[5];
  const float* apb  = (const float*)d_in[6];
  const float* g1   = (const float*)d_in[7];
  const float* b1   = (const float*)d_in[8];
  const float* fw   = (const float*)d_in[9];
  const float* fb   = (const float*)d_in[10];
  const float* pw   = (const float*)d_in[11];
  const float* pb   = (const float*)d_in[12];
  const float* g2   = (const float*)d_in[13];
  const float* b2   = (const float*)d_in[14];

  char* ws = (char*)d_ws;
  size_t off = 0;
  auto alloc = [&](size_t bytes) {
    size_t o = off;
    off += (bytes + 255) & ~(size_t)255;
    return o;
  };
  short* hbf  = (short*)(ws + alloc(8192ull * 768 * 2));   // residual (bf16)
  short* nbf  = (short*)(ws + alloc(8192ull * 768 * 2));   // LN1 out (bf16)
  short* qkvb = (short*)(ws + alloc(8192ull * 2304 * 2));  // Q,K,V row-major
  short* obf  = (short*)(ws + alloc(8192ull * 768 * 2));
  short* aout = (short*)(ws + alloc(2ull * 8192 * 768 * 2));  // split-K partials
  short* gbf  = (short*)(ws + alloc(8192ull * 3072 * 2));
  short* wt_attn = (short*)(ws + alloc(12ull * 768 * 2304 * 2));
  short* wt_proj = (short*)(ws + alloc(12ull * 768 * 768 * 2));
  short* wt_fc   = (short*)(ws + alloc(12ull * 768 * 3072 * 2));
  short* wt_mlp  = (short*)(ws + alloc(12ull * 3072 * 768 * 2));
  short* aout1 = aout + 8192ull * 768;
  (void)ws_size; (void)in_sizes; (void)n_in; (void)out_size;

  wt_transpose<<<dim3(2304 / 32, 768 / 32, 12), 256, 0, stream>>>(caw, wt_attn, 768, 2304);
  wt_transpose<<<dim3(768 / 32, 768 / 32, 12), 256, 0, stream>>>(apw, wt_proj, 768, 768);
  wt_transpose<<<dim3(3072 / 32, 768 / 32, 12), 256, 0, stream>>>(fw, wt_fc, 768, 3072);
  wt_transpose<<<dim3(768 / 32, 3072 / 32, 12), 256, 0, stream>>>(pw, wt_mlp, 3072, 768);

  embed_k<<<8192, 256, 0, stream>>>(x, pos, hbf);

  for (int L = 0; L < 12; ++L) {
    gemm512<1><<<dim3(64, 9), 512, 0, stream>>>(
        hbf, wt_attn + (size_t)L * 2304 * 768, cab + (size_t)L * 2304, qkvb, 2304, 768);
    attn_k<<<dim3(4, 12, 16), 512, 0, stream>>>(qkvb, mask, obf);
    gemm_pk<<<dim3(64, 6, 2), 256, 0, stream>>>(
        obf, wt_proj + (size_t)L * 768 * 768, apb + (size_t)L * 768, aout, 768, 768);
    ln_fused<0><<<2048, 256, 0, stream>>>(hbf, aout, aout1, g1 + (size_t)L * 768,
                                          b1 + (size_t)L * 768, nbf);
    gemm512<2><<<dim3(64, 12), 512, 0, stream>>>(
        nbf, wt_fc + (size_t)L * 768 * 3072, fb + (size_t)L * 3072, gbf, 3072, 768);
    gemm_pk<<<dim3(64, 6, 2), 256, 0, stream>>>(
        gbf, wt_mlp + (size_t)L * 3072 * 768, pb + (size_t)L * 768, aout, 768, 3072);
    if (L < 11) {
      ln_fused<0><<<2048, 256, 0, stream>>>(nbf, aout, aout1, g2 + (size_t)L * 768,
                                            b2 + (size_t)L * 768, hbf);
    } else {
      ln_fused<1><<<2048, 256, 0, stream>>>(nbf, aout, aout1, g2 + (size_t)L * 768,
                                            b2 + (size_t)L * 768, (float*)d_out);
    }
  }
}